// Round 1
// baseline (267.776 us; speedup 1.0000x reference)
//
#include <hip/hip_runtime.h>

// Problem constants (match reference setup_inputs / MAXDISP)
#define MD 4
#define DD 9         // 2*MD+1
#define B  4
#define C  64
#define H  64
#define W  128
#define W4 (W / 4)   // float4 per row = 32

// out[b,c,i,j,y,x] = leaky_relu( ref[b,c,y,x] * tgt[b,c, y+j-MD, x+i-MD] ), 0 if OOB
// Output element count: B*C*DD*DD*H*W = 169,869,312 f32 (~680 MB) -> store-BW bound.

__global__ __launch_bounds__(256) void corr_kernel(const float* __restrict__ ref,
                                                   const float* __restrict__ tgt,
                                                   float* __restrict__ out) {
    const unsigned v = blockIdx.x * 256u + threadIdx.x;  // float4 index
    // total float4 = B*C*DD*DD*H*W4 = 42,467,328 ; grid sized exactly, no guard needed
    unsigned t = v;
    const unsigned x4 = t % W4; t /= W4;   // 32
    const unsigned y  = t % H;  t /= H;    // 64
    const unsigned j  = t % DD; t /= DD;   // 9
    const unsigned i  = t % DD; t /= DD;   // 9
    const unsigned c  = t % C;  t /= C;    // 64
    const unsigned b  = t;

    const unsigned x  = x4 * 4u;
    const unsigned bc = b * C + c;

    // ref row is 16B-aligned at x (x multiple of 4)
    const float4 r = *reinterpret_cast<const float4*>(ref + ((size_t)bc * H + y) * W + x);

    float4 o = make_float4(0.f, 0.f, 0.f, 0.f);
    const int ty = (int)y + (int)j - MD;
    if (ty >= 0 && ty < H) {
        const float* __restrict__ trow = tgt + ((size_t)bc * H + (unsigned)ty) * W;
        const int tx0 = (int)x + (int)i - MD;  // shift breaks 16B alignment -> scalar loads (L2/L3-hot)
        float t0 = 0.f, t1 = 0.f, t2 = 0.f, t3 = 0.f;
        if (tx0 >= 0 && tx0 + 3 < W) {
            t0 = trow[tx0]; t1 = trow[tx0 + 1]; t2 = trow[tx0 + 2]; t3 = trow[tx0 + 3];
        } else {
            if (tx0 + 0 >= 0 && tx0 + 0 < W) t0 = trow[tx0 + 0];
            if (tx0 + 1 >= 0 && tx0 + 1 < W) t1 = trow[tx0 + 1];
            if (tx0 + 2 >= 0 && tx0 + 2 < W) t2 = trow[tx0 + 2];
            if (tx0 + 3 >= 0 && tx0 + 3 < W) t3 = trow[tx0 + 3];
        }
        float p0 = r.x * t0, p1 = r.y * t1, p2 = r.z * t2, p3 = r.w * t3;
        o.x = (p0 > 0.f) ? p0 : 0.1f * p0;
        o.y = (p1 > 0.f) ? p1 : 0.1f * p1;
        o.z = (p2 > 0.f) ? p2 : 0.1f * p2;
        o.w = (p3 > 0.f) ? p3 : 0.1f * p3;
    }
    *reinterpret_cast<float4*>(out + (size_t)v * 4u) = o;
}

extern "C" void kernel_launch(void* const* d_in, const int* in_sizes, int n_in,
                              void* d_out, int out_size, void* d_ws, size_t ws_size,
                              hipStream_t stream) {
    const float* ref = (const float*)d_in[0];
    const float* tgt = (const float*)d_in[1];
    float* out = (float*)d_out;

    const unsigned total_f4 = (unsigned)(B * C) * (DD * DD) * H * W4; // 42,467,328
    const unsigned blocks = total_f4 / 256u;                          // 165,888 exact
    corr_kernel<<<blocks, 256, 0, stream>>>(ref, tgt, out);
}

// Round 2
// 136.722 us; speedup vs baseline: 1.9585x; 1.9585x over previous
//
#include <hip/hip_runtime.h>

// Problem constants
#define MD 4
#define DD 9          // 2*MD+1
#define B  4
#define C  64
#define H  64
#define W  128
#define W4 (W / 4)    // 32 float4 per row
#define HW (H * W)    // 8192 floats per (i,j) slice of one (b,c)

typedef float f32x4 __attribute__((ext_vector_type(4)));

// out[b][c][i][j][y][x] = leaky_relu(ref[b,c,y,x] * tgt[b,c, y+j-4, x+i-4]), 0 OOB.
// One thread per (b,c,y,x4): loads ref f4 once; per j loads a 12-float tgt
// window (3 aligned f4 loads); produces all 9 i-shifted products -> 81 stores.
// Stores are nontemporal: pure write-once stream, keep inputs L2-resident.

__device__ __forceinline__ float lrelu(float p) {
    return fmaxf(p, 0.1f * p);   // == p>0 ? p : 0.1p for all finite p
}

__global__ __launch_bounds__(256) void corr_kernel(const float* __restrict__ ref,
                                                   const float* __restrict__ tgt,
                                                   float* __restrict__ out) {
    // grid: B*C*(H/8) = 2048 blocks; block covers 8 rows of one (b,c) plane.
    const unsigned bc = blockIdx.x >> 3;          // 0..255
    const unsigned yg = blockIdx.x & 7;           // 0..7
    const unsigned x4 = threadIdx.x & 31;         // 0..31
    const unsigned y  = yg * 8 + (threadIdx.x >> 5);
    const unsigned x  = x4 * 4;

    const f32x4 r = *reinterpret_cast<const f32x4*>(ref + ((size_t)bc * H + y) * W + x);

    // out base for (i=0, j=0) at this (b,c,y,x)
    float* const out_base = out + (size_t)bc * (DD * DD * HW) + (size_t)y * W + x;
    const float* const tgt_bc = tgt + (size_t)bc * HW;

    #pragma unroll
    for (int j = 0; j < DD; ++j) {
        const int ty = (int)y + j - MD;
        f32x4 tm = {0.f, 0.f, 0.f, 0.f};
        f32x4 tc = {0.f, 0.f, 0.f, 0.f};
        f32x4 tp = {0.f, 0.f, 0.f, 0.f};
        if (ty >= 0 && ty < H) {
            const float* trow = tgt_bc + (size_t)ty * W;
            if (x4 > 0)  tm = *reinterpret_cast<const f32x4*>(trow + x - 4);
            tc = *reinterpret_cast<const f32x4*>(trow + x);
            if (x4 < W4 - 1) tp = *reinterpret_cast<const f32x4*>(trow + x + 4);
        }
        // 12-float window, all indices static after unroll -> registers
        float t[12] = {tm.x, tm.y, tm.z, tm.w,
                       tc.x, tc.y, tc.z, tc.w,
                       tp.x, tp.y, tp.z, tp.w};

        float* op = out_base + (size_t)j * HW;
        #pragma unroll
        for (int i = 0; i < DD; ++i) {
            f32x4 o;
            o.x = lrelu(r.x * t[i + 0]);
            o.y = lrelu(r.y * t[i + 1]);
            o.z = lrelu(r.z * t[i + 2]);
            o.w = lrelu(r.w * t[i + 3]);
            __builtin_nontemporal_store(o, reinterpret_cast<f32x4*>(op));
            op += (size_t)DD * HW;   // advance i by one: stride DD*HW floats
        }
    }
}

extern "C" void kernel_launch(void* const* d_in, const int* in_sizes, int n_in,
                              void* d_out, int out_size, void* d_ws, size_t ws_size,
                              hipStream_t stream) {
    const float* ref = (const float*)d_in[0];
    const float* tgt = (const float*)d_in[1];
    float* out = (float*)d_out;

    const unsigned blocks = B * C * (H / 8);  // 2048
    corr_kernel<<<blocks, 256, 0, stream>>>(ref, tgt, out);
}